// Round 2
// baseline (339.034 us; speedup 1.0000x reference)
//
#include <hip/hip_runtime.h>
#include <hip/hip_bf16.h>

// Problem constants
#define BB 8
#define CC 128
#define NN 16384            // 128*128 tokens per batch
#define MM (BB * NN)        // 131072
#define NCH 128             // scan chunks per batch-row
#define CLN 128             // chunk length (NN / NCH) == GEMM tile M

typedef __attribute__((ext_vector_type(8))) short short8;   // 8 x bf16 (4 VGPRs)
typedef __attribute__((ext_vector_type(4))) float floatx4;  // MFMA accumulator
typedef unsigned short u16;
typedef unsigned int u32;

__device__ __forceinline__ float bf2f(u16 h) {
  u32 u = ((u32)h) << 16;
  return __builtin_bit_cast(float, u);
}
__device__ __forceinline__ u16 f2bf(float f) {
  u32 u = __builtin_bit_cast(u32, f);
  u32 r = u + 0x7FFFu + ((u >> 16) & 1u);   // round-to-nearest-even
  return (u16)(r >> 16);
}

// ---------------------------------------------------------------------------
// FiLM params: gamma[b,c] = gs[b,:]·cond_gw[c,:] + cond_gb[c]; beta likewise.
__global__ void film_kernel(const float* __restrict__ gs, const float* __restrict__ gw,
                            const float* __restrict__ gb, const float* __restrict__ bw,
                            const float* __restrict__ bb, float* __restrict__ gamma,
                            float* __restrict__ beta) {
  int idx = blockIdx.x * 256 + threadIdx.x;   // 0..1023
  int b = idx >> 7, c = idx & 127;
  float sg = 0.f, sb = 0.f;
  for (int j = 0; j < 128; ++j) {
    float g = gs[b * 128 + j];
    sg += g * gw[c * 128 + j];
    sb += g * bw[c * 128 + j];
  }
  gamma[idx] = sg + gb[c];
  beta[idx] = sb + bb[c];
}

// ---------------------------------------------------------------------------
// Convert all 6 weight tensors (each (2,128,128) f32) to bf16, packed
// [which][block][o][c] at dst + which*32768.
__global__ void convert_kernel(const float* __restrict__ Wk, const float* __restrict__ Wv,
                               const float* __restrict__ Wr, const float* __restrict__ Wo,
                               const float* __restrict__ gp, const float* __restrict__ bp,
                               u16* __restrict__ dst) {
  int idx = blockIdx.x * 256 + threadIdx.x;   // 0..196607
  int which = idx >> 15;
  int off = idx & 32767;
  const float* s;
  switch (which) {
    case 0: s = Wk; break; case 1: s = Wv; break; case 2: s = Wr; break;
    case 3: s = Wo; break; case 4: s = gp; break; default: s = bp; break;
  }
  dst[idx] = f2bf(s[off]);
}

// ---------------------------------------------------------------------------
// Prep: (UPS=1) bilinear 2x upsample + write x_up to out(BCHW) + FiLM + LN -> xn bf16
//       (UPS=0) read out(BCHW) + LN -> xn bf16
template <int UPS>
__global__ __launch_bounds__(256) void prep_kernel(
    const float* __restrict__ src, const float* __restrict__ gamma,
    const float* __restrict__ beta, const float* __restrict__ lng,
    const float* __restrict__ lnb, float* __restrict__ outp, u16* __restrict__ xn) {
  __shared__ float tile[64][129];
  __shared__ float smu[64], srs[64];
  int bidx = blockIdx.x;              // 0..2047
  int half = bidx & 1;
  int ho = (bidx >> 1) & 127;
  int b = bidx >> 8;
  int wo0 = half * 64;
  int tid = threadIdx.x;
  int tk = tid & 63;
  int wo = wo0 + tk;
  int c0 = tid >> 6;                  // 0..3
  int j0 = 0, j1 = 0, i0 = 0, i1 = 0;
  float wy0 = 0.f, wy1 = 0.f, wx0 = 0.f, wx1 = 0.f;
  if (UPS) {
    int jj = ho >> 1;
    if ((ho & 1) == 0) { j0 = jj > 0 ? jj - 1 : 0; j1 = jj; wy0 = 0.25f; wy1 = 0.75f; }
    else               { j0 = jj; j1 = jj < 63 ? jj + 1 : 63; wy0 = 0.75f; wy1 = 0.25f; }
    int ii = wo >> 1;
    if ((wo & 1) == 0) { i0 = ii > 0 ? ii - 1 : 0; i1 = ii; wx0 = 0.25f; wx1 = 0.75f; }
    else               { i0 = ii; i1 = ii < 63 ? ii + 1 : 63; wx0 = 0.75f; wx1 = 0.25f; }
  }
  for (int it = 0; it < 32; ++it) {
    int c = it * 4 + c0;
    float v;
    if (UPS) {
      const float* xp = src + ((size_t)(b * 128 + c)) * 4096;
      v = wy0 * (wx0 * xp[j0 * 64 + i0] + wx1 * xp[j0 * 64 + i1]) +
          wy1 * (wx0 * xp[j1 * 64 + i0] + wx1 * xp[j1 * 64 + i1]);
      outp[((size_t)(b * 128 + c)) * 16384 + ho * 128 + wo] = v;
      v = v * (1.f + gamma[b * 128 + c]) + beta[b * 128 + c];
    } else {
      v = src[((size_t)(b * 128 + c)) * 16384 + ho * 128 + wo];
    }
    tile[tk][c] = v;
  }
  __syncthreads();
  {
    int token = tid >> 2, q = tid & 3;
    float s = 0.f, s2 = 0.f;
    for (int j = 0; j < 32; ++j) { float v = tile[token][q * 32 + j]; s += v; s2 += v * v; }
    s += __shfl_xor(s, 1); s2 += __shfl_xor(s2, 1);
    s += __shfl_xor(s, 2); s2 += __shfl_xor(s2, 2);
    if (q == 0) {
      float mu = s * 0.0078125f;
      float var = s2 * 0.0078125f - mu * mu;
      smu[token] = mu;
      srs[token] = rsqrtf(var + 1e-5f);
    }
  }
  __syncthreads();
  size_t base = ((size_t)b * 16384 + ho * 128 + wo0) * 128;
  for (int it = 0; it < 32; ++it) {
    int idx = it * 256 + tid;
    int token = idx >> 7, c = idx & 127;
    float v = (tile[token][c] - smu[token]) * srs[token] * lng[c] + lnb[c];
    xn[base + idx] = f2bf(v);
  }
}

// ---------------------------------------------------------------------------
// k/v/r GEMM: out[m,o] = sum_c A[m,c]*W[o,c]; k plain bf16, v bf16, r sigmoid bf16.
__global__ __launch_bounds__(256) void gemm_kvr_kernel(
    const u16* __restrict__ A, const u16* __restrict__ W0, const u16* __restrict__ W1,
    const u16* __restrict__ W2, u16* __restrict__ outK, u16* __restrict__ outV,
    u16* __restrict__ outR) {
  __shared__ u16 Alds[128 * 128];
  __shared__ u16 Wlds[128 * 128];
  int tid = threadIdx.x;
  int wave = tid >> 6, lane = tid & 63;
  int l15 = lane & 15, l4 = lane >> 4;
  size_t row0 = (size_t)blockIdx.x * 128;
#pragma unroll
  for (int it = 0; it < 8; ++it) {
    int idx = it * 256 + tid;
    int rr = idx >> 4, s = idx & 15;
    uint4 d = *(const uint4*)(A + (row0 + rr) * 128 + s * 8);
    *(uint4*)(&Alds[rr * 128 + ((s ^ (rr & 15)) << 3)]) = d;
  }
  const u16* Wsarr[3] = {W0, W1, W2};
#pragma unroll
  for (int wsi = 0; wsi < 3; ++wsi) {
#pragma unroll
    for (int it = 0; it < 8; ++it) {
      int idx = it * 256 + tid;
      int rr = idx >> 4, s = idx & 15;
      uint4 d = *(const uint4*)(Wsarr[wsi] + rr * 128 + s * 8);
      *(uint4*)(&Wlds[rr * 128 + ((s ^ (rr & 15)) << 3)]) = d;
    }
    __syncthreads();
    floatx4 acc[2][8];
#pragma unroll
    for (int mi = 0; mi < 2; ++mi)
#pragma unroll
      for (int ni = 0; ni < 8; ++ni) acc[mi][ni] = (floatx4){0.f, 0.f, 0.f, 0.f};
#pragma unroll
    for (int kk = 0; kk < 4; ++kk) {
      int seg = kk * 4 + l4;
      short8 a0 = *(const short8*)(&Alds[(wave * 32 + l15) * 128 + ((seg ^ l15) << 3)]);
      short8 a1 = *(const short8*)(&Alds[(wave * 32 + 16 + l15) * 128 + ((seg ^ l15) << 3)]);
#pragma unroll
      for (int ni = 0; ni < 8; ++ni) {
        short8 bfr = *(const short8*)(&Wlds[(ni * 16 + l15) * 128 + ((seg ^ l15) << 3)]);
        acc[0][ni] = __builtin_amdgcn_mfma_f32_16x16x32_bf16(a0, bfr, acc[0][ni], 0, 0, 0);
        acc[1][ni] = __builtin_amdgcn_mfma_f32_16x16x32_bf16(a1, bfr, acc[1][ni], 0, 0, 0);
      }
    }
#pragma unroll
    for (int mi = 0; mi < 2; ++mi) {
#pragma unroll
      for (int ni = 0; ni < 8; ++ni) {
        int col = ni * 16 + l15;
#pragma unroll
        for (int j = 0; j < 4; ++j) {
          size_t row = row0 + wave * 32 + mi * 16 + l4 * 4 + j;
          float val = acc[mi][ni][j];
          if (wsi == 0) outK[row * 128 + col] = f2bf(val);
          else if (wsi == 1) outV[row * 128 + col] = f2bf(val);
          else outR[row * 128 + col] = f2bf(1.f / (1.f + __expf(-val)));
        }
      }
    }
    __syncthreads();
  }
}

// ---------------------------------------------------------------------------
// Scan phase 1: per chunk local state sums (zero init). 128 chunks x 8 b x 128 c.
__global__ __launch_bounds__(256) void scan1_kernel(const u16* __restrict__ k,
                                                    const float* __restrict__ td,
                                                    float* __restrict__ S) {
  int tid = blockIdx.x * 256 + threadIdx.x;   // 131072
  int c = tid & 127;
  int b = (tid >> 7) & 7;
  int chunk = tid >> 10;                      // 0..127
  float d = __expf(-fmaxf(td[c], 0.f));
  const u16* kp = k + ((size_t)b * 16384 + chunk * 128) * 128 + c;
  float s = 0.f;
#pragma unroll 16
  for (int t = 0; t < CLN; ++t) s = s * d + bf2f(kp[(size_t)t * 128]);
  S[chunk * 1024 + b * 128 + c] = s;
}

// Scan phase 2: per (b,c) scan over 128 chunks; one wave, 2 chunks per lane.
__global__ __launch_bounds__(256) void scan2_kernel(const float* __restrict__ S,
                                                    const float* __restrict__ td,
                                                    float* __restrict__ init) {
  int wave = threadIdx.x >> 6, lane = threadIdx.x & 63;
  int bc = blockIdx.x * 4 + wave;   // 0..1023
  int c = bc & 127;
  float a1 = __expf(-fmaxf(td[c], 0.f) * 128.f);   // decay^CLN
  float s0 = S[(2 * lane) * 1024 + bc];
  float s1 = S[(2 * lane + 1) * 1024 + bc];
  float s = s1 + a1 * s0;   // pair-combined segment sum
  float a = a1 * a1;
  for (int off = 1; off < 64; off <<= 1) {
    float ss = __shfl_up(s, off);
    float aa = __shfl_up(a, off);
    if (lane >= off) { s = s + a * ss; a = a * aa; }
  }
  float e = __shfl_up(s, 1);          // exclusive over pairs
  if (lane == 0) e = 0.f;
  init[(2 * lane) * 1024 + bc] = e;
  init[(2 * lane + 1) * 1024 + bc] = a1 * e + s0;
}

// ---------------------------------------------------------------------------
// Fused tail: scan replay -> y (LDS) -> t = y@Wo^T (LDS) -> g/bt GEMMs ->
// out = out*(1+tanh(g)) + bt with LDS-staged, fully-coalesced RMW.
// Block = (b, chunk of 128 tokens), 256 threads / 4 waves.
__global__ __launch_bounds__(256) void tail_kernel(
    const u16* __restrict__ k, const u16* __restrict__ v, const u16* __restrict__ r,
    const float* __restrict__ init, const float* __restrict__ td,
    const u16* __restrict__ Wo, const u16* __restrict__ Wg, const u16* __restrict__ Wb,
    const float* __restrict__ gpb, const float* __restrict__ bpb,
    float* __restrict__ outp) {
  __shared__ u32 SMEM[16384];                // 64 KB
  u16* Y  = (u16*)SMEM;                      // [tok][c] bf16, swizzled
  u16* T2 = ((u16*)SMEM) + 16384;            // [tok][o] bf16, swizzled
  u32* MB = SMEM;                            // [o][swz(tok)] packed (m, bt)

  int tid = threadIdx.x;
  int wave = tid >> 6, lane = tid & 63;
  int l15 = lane & 15, l4 = lane >> 4;
  int b = blockIdx.x >> 7;
  int chunk = blockIdx.x & 127;
  size_t ebase = ((size_t)b * 16384 + (size_t)chunk * 128) * 128;

  // Per-wave weight fragments (blend orientation: A = weight rows o).
  int ob = wave * 32;
  short8 wof[2][4], wgf[2][4], wbf2[2][4];
#pragma unroll
  for (int mi = 0; mi < 2; ++mi)
#pragma unroll
    for (int kk = 0; kk < 4; ++kk) {
      int o = ob + mi * 16 + l15;
      wof[mi][kk]  = *(const short8*)(Wo + o * 128 + kk * 32 + l4 * 8);
      wgf[mi][kk]  = *(const short8*)(Wg + o * 128 + kk * 32 + l4 * 8);
      wbf2[mi][kk] = *(const short8*)(Wb + o * 128 + kk * 32 + l4 * 8);
    }

  // Scan replay: threads 0..127 (waves 0-1), one channel each, coalesced reads.
  if (tid < 128) {
    int c = tid;
    float d = __expf(-fmaxf(td[c], 0.f));
    float s = init[chunk * 1024 + b * 128 + c];
    const u16* kp = k + ebase + c;
    const u16* vp = v + ebase + c;
    const u16* rp = r + ebase + c;
    int seg = c >> 3, cl = c & 7;
#pragma unroll 8
    for (int t = 0; t < 128; ++t) {
      s = s * d + bf2f(kp[(size_t)t * 128]);
      float y = bf2f(rp[(size_t)t * 128]) * (s + bf2f(vp[(size_t)t * 128]));
      Y[t * 128 + (((seg ^ (t & 15)) << 3) | cl)] = f2bf(y);
    }
  }
  __syncthreads();

  // GEMM1: t[o][tok] = Wo · y^T  (D rows = o, cols = tok)
  floatx4 acc[2][8];
#pragma unroll
  for (int mi = 0; mi < 2; ++mi)
#pragma unroll
    for (int ni = 0; ni < 8; ++ni) acc[mi][ni] = (floatx4){0.f, 0.f, 0.f, 0.f};
#pragma unroll
  for (int kk = 0; kk < 4; ++kk) {
    int seg = kk * 4 + l4;
#pragma unroll
    for (int ni = 0; ni < 8; ++ni) {
      short8 yf = *(const short8*)(&Y[(ni * 16 + l15) * 128 + ((seg ^ l15) << 3)]);
#pragma unroll
      for (int mi = 0; mi < 2; ++mi)
        acc[mi][ni] = __builtin_amdgcn_mfma_f32_16x16x32_bf16(wof[mi][kk], yf, acc[mi][ni], 0, 0, 0);
    }
  }
  // Write t to T2 as [tok][o] bf16 (swizzled), packed pairs of consecutive o.
#pragma unroll
  for (int mi = 0; mi < 2; ++mi)
#pragma unroll
    for (int ni = 0; ni < 8; ++ni) {
      int tok = ni * 16 + l15;
#pragma unroll
      for (int j = 0; j < 4; j += 2) {
        int o = ob + mi * 16 + l4 * 4 + j;
        u32 pack = (u32)f2bf(acc[mi][ni][j]) | ((u32)f2bf(acc[mi][ni][j + 1]) << 16);
        int pos = tok * 128 + ((((o >> 3) ^ (tok & 15)) << 3) | (o & 7));
        *(u32*)(T2 + pos) = pack;
      }
    }
  __syncthreads();

  // GEMM2: g[o'][tok] = gp · t^T, bt likewise.
  floatx4 ag[2][8], ab[2][8];
#pragma unroll
  for (int mi = 0; mi < 2; ++mi)
#pragma unroll
    for (int ni = 0; ni < 8; ++ni) {
      ag[mi][ni] = (floatx4){0.f, 0.f, 0.f, 0.f};
      ab[mi][ni] = (floatx4){0.f, 0.f, 0.f, 0.f};
    }
#pragma unroll
  for (int kk = 0; kk < 4; ++kk) {
    int seg = kk * 4 + l4;
#pragma unroll
    for (int ni = 0; ni < 8; ++ni) {
      short8 tf = *(const short8*)(&T2[(ni * 16 + l15) * 128 + ((seg ^ l15) << 3)]);
#pragma unroll
      for (int mi = 0; mi < 2; ++mi) {
        ag[mi][ni] = __builtin_amdgcn_mfma_f32_16x16x32_bf16(wgf[mi][kk], tf, ag[mi][ni], 0, 0, 0);
        ab[mi][ni] = __builtin_amdgcn_mfma_f32_16x16x32_bf16(wbf2[mi][kk], tf, ab[mi][ni], 0, 0, 0);
      }
    }
  }
  __syncthreads();   // everyone done reading T2 before SMEM reused as MB

  // Stage (m = 1+tanh(g), bt) packed bf16 into LDS at [o][swizzled tok].
#pragma unroll
  for (int mi = 0; mi < 2; ++mi)
#pragma unroll
    for (int ni = 0; ni < 8; ++ni) {
      int tok = ni * 16 + l15;
#pragma unroll
      for (int j = 0; j < 4; ++j) {
        int o = ob + mi * 16 + l4 * 4 + j;
        float g = ag[mi][ni][j] + gpb[o];
        float m = 1.f + tanhf(g);
        float bt = ab[mi][ni][j] + bpb[o];
        MB[o * 128 + ((((tok >> 3) ^ (o & 15)) << 3) | (tok & 7))] =
            (u32)f2bf(m) | ((u32)f2bf(bt) << 16);
      }
    }
  __syncthreads();

  // Final RMW: 512B-contiguous per 16 lanes, float4 loads/stores.
#pragma unroll
  for (int it = 0; it < 8; ++it) {
    int idx = it * 256 + tid;
    int o = idx >> 4, seg = idx & 15;
    int sp = ((seg ^ (o & 15)) << 3);
    uint4 mb0 = *(const uint4*)(&MB[o * 128 + sp]);
    uint4 mb1 = *(const uint4*)(&MB[o * 128 + sp + 4]);
    float* op = outp + ((size_t)(b * 128 + o)) * 16384 + chunk * 128 + seg * 8;
    float4 o0 = *(float4*)op;
    float4 o1 = *(float4*)(op + 4);
    o0.x = o0.x * bf2f((u16)(mb0.x & 0xffff)) + bf2f((u16)(mb0.x >> 16));
    o0.y = o0.y * bf2f((u16)(mb0.y & 0xffff)) + bf2f((u16)(mb0.y >> 16));
    o0.z = o0.z * bf2f((u16)(mb0.z & 0xffff)) + bf2f((u16)(mb0.z >> 16));
    o0.w = o0.w * bf2f((u16)(mb0.w & 0xffff)) + bf2f((u16)(mb0.w >> 16));
    o1.x = o1.x * bf2f((u16)(mb1.x & 0xffff)) + bf2f((u16)(mb1.x >> 16));
    o1.y = o1.y * bf2f((u16)(mb1.y & 0xffff)) + bf2f((u16)(mb1.y >> 16));
    o1.z = o1.z * bf2f((u16)(mb1.z & 0xffff)) + bf2f((u16)(mb1.z >> 16));
    o1.w = o1.w * bf2f((u16)(mb1.w & 0xffff)) + bf2f((u16)(mb1.w >> 16));
    *(float4*)op = o0;
    *(float4*)(op + 4) = o1;
  }
}

// ---------------------------------------------------------------------------
extern "C" void kernel_launch(void* const* d_in, const int* in_sizes, int n_in,
                              void* d_out, int out_size, void* d_ws, size_t ws_size,
                              hipStream_t stream) {
  const float* x        = (const float*)d_in[0];
  const float* gs       = (const float*)d_in[1];
  const float* cond_gw  = (const float*)d_in[2];
  const float* cond_gb  = (const float*)d_in[3];
  const float* cond_bw  = (const float*)d_in[4];
  const float* cond_bb  = (const float*)d_in[5];
  const float* td       = (const float*)d_in[6];
  const float* Wk       = (const float*)d_in[7];
  const float* Wv       = (const float*)d_in[8];
  const float* Wr       = (const float*)d_in[9];
  const float* Wo       = (const float*)d_in[10];
  const float* ln_g     = (const float*)d_in[11];
  const float* ln_b     = (const float*)d_in[12];
  const float* gp_w     = (const float*)d_in[13];
  const float* gp_b     = (const float*)d_in[14];
  const float* bp_w     = (const float*)d_in[15];
  const float* bp_b     = (const float*)d_in[16];
  float* outp = (float*)d_out;

  char* w = (char*)d_ws;
  float* gamma = (float*)w; w += 4096;
  float* beta  = (float*)w; w += 4096;
  u16* wbf     = (u16*)w;   w += 6 * 2 * 16384 * sizeof(u16);     // 384 KB
  u16* xn      = (u16*)w;   w += (size_t)MM * 128 * sizeof(u16);  // 32 MB
  u16* kbuf    = (u16*)w;   w += (size_t)MM * 128 * sizeof(u16);  // 32 MB
  u16* vbuf    = (u16*)w;   w += (size_t)MM * 128 * sizeof(u16);  // 32 MB
  u16* rbuf    = (u16*)w;   w += (size_t)MM * 128 * sizeof(u16);  // 32 MB
  float* Sbuf  = (float*)w; w += NCH * 1024 * sizeof(float);      // 512 KB
  float* ibuf  = (float*)w; w += NCH * 1024 * sizeof(float);      // 512 KB

  film_kernel<<<4, 256, 0, stream>>>(gs, cond_gw, cond_gb, cond_bw, cond_bb, gamma, beta);
  convert_kernel<<<768, 256, 0, stream>>>(Wk, Wv, Wr, Wo, gp_w, bp_w, wbf);

  for (int blk = 0; blk < 2; ++blk) {
    const u16* bWk = wbf + 0 * 32768 + blk * 16384;
    const u16* bWv = wbf + 1 * 32768 + blk * 16384;
    const u16* bWr = wbf + 2 * 32768 + blk * 16384;
    const u16* bWo = wbf + 3 * 32768 + blk * 16384;
    const u16* bGp = wbf + 4 * 32768 + blk * 16384;
    const u16* bBp = wbf + 5 * 32768 + blk * 16384;
    const float* tdi = td + blk * 128;

    if (blk == 0)
      prep_kernel<1><<<2048, 256, 0, stream>>>(x, gamma, beta, ln_g, ln_b, outp, xn);
    else
      prep_kernel<0><<<2048, 256, 0, stream>>>(outp, nullptr, nullptr, ln_g + 128,
                                               ln_b + 128, nullptr, xn);

    gemm_kvr_kernel<<<1024, 256, 0, stream>>>(xn, bWk, bWv, bWr, kbuf, vbuf, rbuf);
    scan1_kernel<<<512, 256, 0, stream>>>(kbuf, tdi, Sbuf);
    scan2_kernel<<<256, 256, 0, stream>>>(Sbuf, tdi, ibuf);
    tail_kernel<<<1024, 256, 0, stream>>>(kbuf, vbuf, rbuf, ibuf, tdi,
                                          bWo, bGp, bBp, gp_b + blk * 128,
                                          bp_b + blk * 128, outp);
  }
}

// Round 3
// 265.729 us; speedup vs baseline: 1.2759x; 1.2759x over previous
//
#include <hip/hip_runtime.h>
#include <hip/hip_bf16.h>

// Problem constants
#define BB 8
#define CC 128
#define NN 16384            // 128*128 tokens per batch
#define MM (BB * NN)        // 131072
#define NCH 128             // scan chunks per batch-row
#define CLN 128             // chunk length == GEMM tile M

typedef __attribute__((ext_vector_type(8))) short short8;   // 8 x bf16 (4 VGPRs)
typedef __attribute__((ext_vector_type(4))) float floatx4;  // MFMA accumulator
typedef unsigned short u16;
typedef unsigned int u32;

__device__ __forceinline__ float bf2f(u16 h) {
  u32 u = ((u32)h) << 16;
  return __builtin_bit_cast(float, u);
}
__device__ __forceinline__ u16 f2bf(float f) {
  u32 u = __builtin_bit_cast(u32, f);
  u32 r = u + 0x7FFFu + ((u >> 16) & 1u);   // round-to-nearest-even
  return (u16)(r >> 16);
}

// ---------------------------------------------------------------------------
// FiLM params: gamma[b,c] = gs[b,:]·cond_gw[c,:] + cond_gb[c]; beta likewise.
__global__ void film_kernel(const float* __restrict__ gs, const float* __restrict__ gw,
                            const float* __restrict__ gb, const float* __restrict__ bw,
                            const float* __restrict__ bb, float* __restrict__ gamma,
                            float* __restrict__ beta) {
  int idx = blockIdx.x * 256 + threadIdx.x;   // 0..1023
  int b = idx >> 7, c = idx & 127;
  float sg = 0.f, sb = 0.f;
  for (int j = 0; j < 128; ++j) {
    float g = gs[b * 128 + j];
    sg += g * gw[c * 128 + j];
    sb += g * bw[c * 128 + j];
  }
  gamma[idx] = sg + gb[c];
  beta[idx] = sb + bb[c];
}

// ---------------------------------------------------------------------------
// Convert all 6 weight tensors (each (2,128,128) f32) to bf16, packed
// [which][block][o][c] at dst + which*32768.
__global__ void convert_kernel(const float* __restrict__ Wk, const float* __restrict__ Wv,
                               const float* __restrict__ Wr, const float* __restrict__ Wo,
                               const float* __restrict__ gp, const float* __restrict__ bp,
                               u16* __restrict__ dst) {
  int idx = blockIdx.x * 256 + threadIdx.x;   // 0..196607
  int which = idx >> 15;
  int off = idx & 32767;
  const float* s;
  switch (which) {
    case 0: s = Wk; break; case 1: s = Wv; break; case 2: s = Wr; break;
    case 3: s = Wo; break; case 4: s = gp; break; default: s = bp; break;
  }
  dst[idx] = f2bf(s[off]);
}

// ---------------------------------------------------------------------------
// Prep: (UPS=1) bilinear 2x upsample + write x_up to out(BCHW) + FiLM + LN -> xn bf16
//       (UPS=0) read out(BCHW) + LN -> xn bf16
template <int UPS>
__global__ __launch_bounds__(256) void prep_kernel(
    const float* __restrict__ src, const float* __restrict__ gamma,
    const float* __restrict__ beta, const float* __restrict__ lng,
    const float* __restrict__ lnb, float* __restrict__ outp, u16* __restrict__ xn) {
  __shared__ float tile[64][129];
  __shared__ float smu[64], srs[64];
  int bidx = blockIdx.x;              // 0..2047
  int half = bidx & 1;
  int ho = (bidx >> 1) & 127;
  int b = bidx >> 8;
  int wo0 = half * 64;
  int tid = threadIdx.x;
  int tk = tid & 63;
  int wo = wo0 + tk;
  int c0 = tid >> 6;                  // 0..3
  int j0 = 0, j1 = 0, i0 = 0, i1 = 0;
  float wy0 = 0.f, wy1 = 0.f, wx0 = 0.f, wx1 = 0.f;
  if (UPS) {
    int jj = ho >> 1;
    if ((ho & 1) == 0) { j0 = jj > 0 ? jj - 1 : 0; j1 = jj; wy0 = 0.25f; wy1 = 0.75f; }
    else               { j0 = jj; j1 = jj < 63 ? jj + 1 : 63; wy0 = 0.75f; wy1 = 0.25f; }
    int ii = wo >> 1;
    if ((wo & 1) == 0) { i0 = ii > 0 ? ii - 1 : 0; i1 = ii; wx0 = 0.25f; wx1 = 0.75f; }
    else               { i0 = ii; i1 = ii < 63 ? ii + 1 : 63; wx0 = 0.75f; wx1 = 0.25f; }
  }
  for (int it = 0; it < 32; ++it) {
    int c = it * 4 + c0;
    float v;
    if (UPS) {
      const float* xp = src + ((size_t)(b * 128 + c)) * 4096;
      v = wy0 * (wx0 * xp[j0 * 64 + i0] + wx1 * xp[j0 * 64 + i1]) +
          wy1 * (wx0 * xp[j1 * 64 + i0] + wx1 * xp[j1 * 64 + i1]);
      outp[((size_t)(b * 128 + c)) * 16384 + ho * 128 + wo] = v;
      v = v * (1.f + gamma[b * 128 + c]) + beta[b * 128 + c];
    } else {
      v = src[((size_t)(b * 128 + c)) * 16384 + ho * 128 + wo];
    }
    tile[tk][c] = v;
  }
  __syncthreads();
  {
    int token = tid >> 2, q = tid & 3;
    float s = 0.f, s2 = 0.f;
    for (int j = 0; j < 32; ++j) { float v = tile[token][q * 32 + j]; s += v; s2 += v * v; }
    s += __shfl_xor(s, 1); s2 += __shfl_xor(s2, 1);
    s += __shfl_xor(s, 2); s2 += __shfl_xor(s2, 2);
    if (q == 0) {
      float mu = s * 0.0078125f;
      float var = s2 * 0.0078125f - mu * mu;
      smu[token] = mu;
      srs[token] = rsqrtf(var + 1e-5f);
    }
  }
  __syncthreads();
  size_t base = ((size_t)b * 16384 + ho * 128 + wo0) * 128;
  for (int it = 0; it < 32; ++it) {
    int idx = it * 256 + tid;
    int token = idx >> 7, c = idx & 127;
    float v = (tile[token][c] - smu[token]) * srs[token] * lng[c] + lnb[c];
    xn[base + idx] = f2bf(v);
  }
}

// ---------------------------------------------------------------------------
// k/v/r GEMM + fused chunk-scan partial sums.
// out[m,o] = sum_c A[m,c]*W[o,c]; wsi==0 also computes S[chunk] = sum d^{127-t} k_t.
__global__ __launch_bounds__(256) void gemm_kvr_kernel(
    const u16* __restrict__ A, const u16* __restrict__ W0, const u16* __restrict__ W1,
    const u16* __restrict__ W2, const float* __restrict__ td, u16* __restrict__ outK,
    u16* __restrict__ outV, u16* __restrict__ outR, float* __restrict__ Sbuf) {
  __shared__ u16 Alds[128 * 128];
  __shared__ u16 Wlds[128 * 128];
  __shared__ float Sred[512];         // [wave][c]
  int tid = threadIdx.x;
  int wave = tid >> 6, lane = tid & 63;
  int l15 = lane & 15, l4 = lane >> 4;
  size_t row0 = (size_t)blockIdx.x * 128;
#pragma unroll
  for (int it = 0; it < 8; ++it) {
    int idx = it * 256 + tid;
    int rr = idx >> 4, s = idx & 15;
    uint4 d = *(const uint4*)(A + (row0 + rr) * 128 + s * 8);
    *(uint4*)(&Alds[rr * 128 + ((s ^ (rr & 15)) << 3)]) = d;
  }
  const u16* Wsarr[3] = {W0, W1, W2};
#pragma unroll
  for (int wsi = 0; wsi < 3; ++wsi) {
#pragma unroll
    for (int it = 0; it < 8; ++it) {
      int idx = it * 256 + tid;
      int rr = idx >> 4, s = idx & 15;
      uint4 d = *(const uint4*)(Wsarr[wsi] + rr * 128 + s * 8);
      *(uint4*)(&Wlds[rr * 128 + ((s ^ (rr & 15)) << 3)]) = d;
    }
    __syncthreads();
    floatx4 acc[2][8];
#pragma unroll
    for (int mi = 0; mi < 2; ++mi)
#pragma unroll
      for (int ni = 0; ni < 8; ++ni) acc[mi][ni] = (floatx4){0.f, 0.f, 0.f, 0.f};
#pragma unroll
    for (int kk = 0; kk < 4; ++kk) {
      int seg = kk * 4 + l4;
      short8 a0 = *(const short8*)(&Alds[(wave * 32 + l15) * 128 + ((seg ^ l15) << 3)]);
      short8 a1 = *(const short8*)(&Alds[(wave * 32 + 16 + l15) * 128 + ((seg ^ l15) << 3)]);
#pragma unroll
      for (int ni = 0; ni < 8; ++ni) {
        short8 bfr = *(const short8*)(&Wlds[(ni * 16 + l15) * 128 + ((seg ^ l15) << 3)]);
        acc[0][ni] = __builtin_amdgcn_mfma_f32_16x16x32_bf16(a0, bfr, acc[0][ni], 0, 0, 0);
        acc[1][ni] = __builtin_amdgcn_mfma_f32_16x16x32_bf16(a1, bfr, acc[1][ni], 0, 0, 0);
      }
    }
#pragma unroll
    for (int mi = 0; mi < 2; ++mi) {
#pragma unroll
      for (int ni = 0; ni < 8; ++ni) {
        int col = ni * 16 + l15;
#pragma unroll
        for (int j = 0; j < 4; ++j) {
          size_t row = row0 + wave * 32 + mi * 16 + l4 * 4 + j;
          float val = acc[mi][ni][j];
          if (wsi == 0) outK[row * 128 + col] = f2bf(val);
          else if (wsi == 1) outV[row * 128 + col] = f2bf(val);
          else outR[row * 128 + col] = f2bf(1.f / (1.f + __expf(-val)));
        }
      }
    }
    if (wsi == 0) {
      // Fused scan1: S_c = sum_tau d_c^{127-tau} k[tau][c]; tau = wave*32+mi*16+l4*4+j
      int T0 = wave * 32 + l4 * 4;
#pragma unroll
      for (int ni = 0; ni < 8; ++ni) {
        int c = ni * 16 + l15;
        float a = fmaxf(td[c], 0.f);
        float E = __expf(-a * (float)(127 - T0));   // d^{127-T0}
        float r1 = __expf(a);                        // d^{-1}
        float r2 = r1 * r1, r4 = r2 * r2, r8 = r4 * r4, r16 = r8 * r8;
        float w = E, sum;
        sum  = w * acc[0][ni][0]; w *= r1;
        sum += w * acc[0][ni][1]; w *= r1;
        sum += w * acc[0][ni][2]; w *= r1;
        sum += w * acc[0][ni][3];
        w = E * r16;
        sum += w * acc[1][ni][0]; w *= r1;
        sum += w * acc[1][ni][1]; w *= r1;
        sum += w * acc[1][ni][2]; w *= r1;
        sum += w * acc[1][ni][3];
        sum += __shfl_xor(sum, 16);
        sum += __shfl_xor(sum, 32);
        if (l4 == 0) Sred[wave * 128 + c] = sum;
      }
    }
    __syncthreads();
    if (wsi == 0 && tid < 128) {
      float s = Sred[tid] + Sred[128 + tid] + Sred[256 + tid] + Sred[384 + tid];
      Sbuf[(blockIdx.x & 127) * 1024 + (blockIdx.x >> 7) * 128 + tid] = s;
    }
  }
}

// ---------------------------------------------------------------------------
// Scan phase 2: per (b,c) scan over 128 chunks; one wave, 2 chunks per lane.
__global__ __launch_bounds__(256) void scan2_kernel(const float* __restrict__ S,
                                                    const float* __restrict__ td,
                                                    float* __restrict__ init) {
  int wave = threadIdx.x >> 6, lane = threadIdx.x & 63;
  int bc = blockIdx.x * 4 + wave;   // 0..1023
  int c = bc & 127;
  float a1 = __expf(-fmaxf(td[c], 0.f) * 128.f);   // decay^CLN
  float s0 = S[(2 * lane) * 1024 + bc];
  float s1 = S[(2 * lane + 1) * 1024 + bc];
  float s = s1 + a1 * s0;   // pair-combined segment sum
  float a = a1 * a1;
  for (int off = 1; off < 64; off <<= 1) {
    float ss = __shfl_up(s, off);
    float aa = __shfl_up(a, off);
    if (lane >= off) { s = s + a * ss; a = a * aa; }
  }
  float e = __shfl_up(s, 1);          // exclusive over pairs
  if (lane == 0) e = 0.f;
  init[(2 * lane) * 1024 + bc] = e;
  init[(2 * lane + 1) * 1024 + bc] = a1 * e + s0;
}

// ---------------------------------------------------------------------------
// Fused tail v2: 512 thr / 8 waves, 34 KB LDS, sub-chunked scan (4x32 tokens).
// scan replay -> Y (LDS) -> t = Wo·Y^T -> T2 (LDS, reused) -> g/bt GEMMs ->
// out = out*(1+tanh(g)) + bt, staged via MB (LDS, reused, two halves).
__global__ __launch_bounds__(512, 4) void tail_kernel(
    const u16* __restrict__ k, const u16* __restrict__ v, const u16* __restrict__ r,
    const float* __restrict__ init, const float* __restrict__ td,
    const u16* __restrict__ Wo, const u16* __restrict__ Wg, const u16* __restrict__ Wb,
    const float* __restrict__ gpb, const float* __restrict__ bpb,
    float* __restrict__ outp) {
  __shared__ u32 SMEM[8192];          // 32 KB: Y -> T2 -> MB
  __shared__ float SC[512];           // sub-chunk sums [sub][c]
  u16* Y = (u16*)SMEM;
  u16* T2 = (u16*)SMEM;
  u32* MB = SMEM;

  int tid = threadIdx.x;
  int wave = tid >> 6, lane = tid & 63;
  int l15 = lane & 15, l4 = lane >> 4;
  int b = blockIdx.x >> 7;
  int chunk = blockIdx.x & 127;
  size_t ebase = ((size_t)b * 16384 + (size_t)chunk * 128) * 128;

  // ---- Scan: thread = (channel c, sub-chunk of 32 tokens) ----
  {
    int c = tid & 127;
    int sub = tid >> 7;               // 0..3
    float a = fmaxf(td[c], 0.f);
    float d = __expf(-a);
    const u16* kp = k + ebase + (size_t)sub * 32 * 128 + c;
    const u16* vp = v + ebase + (size_t)sub * 32 * 128 + c;
    const u16* rp = r + ebase + (size_t)sub * 32 * 128 + c;
    float s = 0.f;
#pragma unroll
    for (int t = 0; t < 32; ++t) s = s * d + bf2f(kp[t * 128]);
    SC[sub * 128 + c] = s;
    __syncthreads();
    float st = init[chunk * 1024 + b * 128 + c];
    float d32 = __expf(-a * 32.f);
    for (int j = 0; j < sub; ++j) st = st * d32 + SC[j * 128 + c];
    int cs = c >> 3, cl = c & 7;
#pragma unroll
    for (int t = 0; t < 32; ++t) {
      int tg = sub * 32 + t;
      st = st * d + bf2f(kp[t * 128]);
      float y = bf2f(rp[t * 128]) * (st + bf2f(vp[t * 128]));
      Y[tg * 128 + (((cs ^ (tg & 15)) << 3) | cl)] = f2bf(y);
    }
  }
  __syncthreads();

  // ---- GEMM1: t[o][tok] = Wo(16 rows/wave) · Y^T ----
  int ob = wave * 16;
  short8 wof[4];
#pragma unroll
  for (int kk = 0; kk < 4; ++kk)
    wof[kk] = *(const short8*)(Wo + (ob + l15) * 128 + kk * 32 + l4 * 8);
  floatx4 acc[8];
#pragma unroll
  for (int ni = 0; ni < 8; ++ni) acc[ni] = (floatx4){0.f, 0.f, 0.f, 0.f};
#pragma unroll
  for (int kk = 0; kk < 4; ++kk) {
    int seg = kk * 4 + l4;
#pragma unroll
    for (int ni = 0; ni < 8; ++ni) {
      short8 yf = *(const short8*)(&Y[(ni * 16 + l15) * 128 + ((seg ^ l15) << 3)]);
      acc[ni] = __builtin_amdgcn_mfma_f32_16x16x32_bf16(wof[kk], yf, acc[ni], 0, 0, 0);
    }
  }
  __syncthreads();   // all Y reads complete before overwrite

  // write T2 [tok][o] bf16, swizzled, packed o-pairs
#pragma unroll
  for (int ni = 0; ni < 8; ++ni) {
    int tok = ni * 16 + l15;
#pragma unroll
    for (int j = 0; j < 4; j += 2) {
      int o = ob + l4 * 4 + j;
      u32 pack = (u32)f2bf(acc[ni][j]) | ((u32)f2bf(acc[ni][j + 1]) << 16);
      int pos = tok * 128 + ((((o >> 3) ^ (tok & 15)) << 3) | (o & 7));
      *(u32*)(T2 + pos) = pack;
    }
  }
  __syncthreads();

  // ---- GEMM2: g/bt [o'][tok] over K=o ----
  short8 wgf[4], wbf2[4];
#pragma unroll
  for (int kk = 0; kk < 4; ++kk) {
    wgf[kk]  = *(const short8*)(Wg + (ob + l15) * 128 + kk * 32 + l4 * 8);
    wbf2[kk] = *(const short8*)(Wb + (ob + l15) * 128 + kk * 32 + l4 * 8);
  }
  floatx4 ag[8], ab[8];
#pragma unroll
  for (int ni = 0; ni < 8; ++ni) {
    ag[ni] = (floatx4){0.f, 0.f, 0.f, 0.f};
    ab[ni] = (floatx4){0.f, 0.f, 0.f, 0.f};
  }
#pragma unroll
  for (int kk = 0; kk < 4; ++kk) {
    int seg = kk * 4 + l4;
#pragma unroll
    for (int ni = 0; ni < 8; ++ni) {
      short8 tf = *(const short8*)(&T2[(ni * 16 + l15) * 128 + ((seg ^ l15) << 3)]);
      ag[ni] = __builtin_amdgcn_mfma_f32_16x16x32_bf16(wgf[kk], tf, ag[ni], 0, 0, 0);
      ab[ni] = __builtin_amdgcn_mfma_f32_16x16x32_bf16(wbf2[kk], tf, ab[ni], 0, 0, 0);
    }
  }
  __syncthreads();   // T2 fully consumed

  // ---- Epilogue in two o-halves of 64 (MB = 32 KB) ----
#pragma unroll
  for (int h = 0; h < 2; ++h) {
    if ((wave >> 2) == h) {
      int orel0 = (wave & 3) * 16;
#pragma unroll
      for (int ni = 0; ni < 8; ++ni) {
        int tok = ni * 16 + l15;
#pragma unroll
        for (int j = 0; j < 4; ++j) {
          int orel = orel0 + l4 * 4 + j;
          int o = h * 64 + orel;
          float g = ag[ni][j] + gpb[o];
          float t1 = __expf(2.f * g);
          float m = 2.f - 2.f / (t1 + 1.f);          // 1 + tanh(g), inf-safe
          float bt = ab[ni][j] + bpb[o];
          int rot = ((orel & 3) << 2) | ((orel >> 2) & 3);
          MB[orel * 128 + ((((tok >> 3) ^ rot) << 3) | (tok & 7))] =
              (u32)f2bf(m) | ((u32)f2bf(bt) << 16);
        }
      }
    }
    __syncthreads();
#pragma unroll
    for (int it = 0; it < 2; ++it) {
      int idx = it * 512 + tid;
      int orel = idx >> 4, seg = idx & 15;
      int o = h * 64 + orel;
      int rot = ((orel & 3) << 2) | ((orel >> 2) & 3);
      int sp = ((seg ^ rot) << 3);
      uint4 mb0 = *(const uint4*)(&MB[orel * 128 + sp]);
      uint4 mb1 = *(const uint4*)(&MB[orel * 128 + sp + 4]);
      float* op = outp + ((size_t)(b * 128 + o)) * 16384 + chunk * 128 + seg * 8;
      float4 o0 = *(float4*)op;
      float4 o1 = *(float4*)(op + 4);
      o0.x = o0.x * bf2f((u16)(mb0.x & 0xffff)) + bf2f((u16)(mb0.x >> 16));
      o0.y = o0.y * bf2f((u16)(mb0.y & 0xffff)) + bf2f((u16)(mb0.y >> 16));
      o0.z = o0.z * bf2f((u16)(mb0.z & 0xffff)) + bf2f((u16)(mb0.z >> 16));
      o0.w = o0.w * bf2f((u16)(mb0.w & 0xffff)) + bf2f((u16)(mb0.w >> 16));
      o1.x = o1.x * bf2f((u16)(mb1.x & 0xffff)) + bf2f((u16)(mb1.x >> 16));
      o1.y = o1.y * bf2f((u16)(mb1.y & 0xffff)) + bf2f((u16)(mb1.y >> 16));
      o1.z = o1.z * bf2f((u16)(mb1.z & 0xffff)) + bf2f((u16)(mb1.z >> 16));
      o1.w = o1.w * bf2f((u16)(mb1.w & 0xffff)) + bf2f((u16)(mb1.w >> 16));
      *(float4*)op = o0;
      *(float4*)(op + 4) = o1;
    }
    __syncthreads();
  }
}

// ---------------------------------------------------------------------------
extern "C" void kernel_launch(void* const* d_in, const int* in_sizes, int n_in,
                              void* d_out, int out_size, void* d_ws, size_t ws_size,
                              hipStream_t stream) {
  const float* x        = (const float*)d_in[0];
  const float* gs       = (const float*)d_in[1];
  const float* cond_gw  = (const float*)d_in[2];
  const float* cond_gb  = (const float*)d_in[3];
  const float* cond_bw  = (const float*)d_in[4];
  const float* cond_bb  = (const float*)d_in[5];
  const float* td       = (const float*)d_in[6];
  const float* Wk       = (const float*)d_in[7];
  const float* Wv       = (const float*)d_in[8];
  const float* Wr       = (const float*)d_in[9];
  const float* Wo       = (const float*)d_in[10];
  const float* ln_g     = (const float*)d_in[11];
  const float* ln_b     = (const float*)d_in[12];
  const float* gp_w     = (const float*)d_in[13];
  const float* gp_b     = (const float*)d_in[14];
  const float* bp_w     = (const float*)d_in[15];
  const float* bp_b     = (const float*)d_in[16];
  float* outp = (float*)d_out;

  char* w = (char*)d_ws;
  float* gamma = (float*)w; w += 4096;
  float* beta  = (float*)w; w += 4096;
  u16* wbf     = (u16*)w;   w += 6 * 2 * 16384 * sizeof(u16);     // 384 KB
  u16* xn      = (u16*)w;   w += (size_t)MM * 128 * sizeof(u16);  // 32 MB
  u16* kbuf    = (u16*)w;   w += (size_t)MM * 128 * sizeof(u16);  // 32 MB
  u16* vbuf    = (u16*)w;   w += (size_t)MM * 128 * sizeof(u16);  // 32 MB
  u16* rbuf    = (u16*)w;   w += (size_t)MM * 128 * sizeof(u16);  // 32 MB
  float* Sbuf  = (float*)w; w += NCH * 1024 * sizeof(float);      // 512 KB
  float* ibuf  = (float*)w; w += NCH * 1024 * sizeof(float);      // 512 KB

  film_kernel<<<4, 256, 0, stream>>>(gs, cond_gw, cond_gb, cond_bw, cond_bb, gamma, beta);
  convert_kernel<<<768, 256, 0, stream>>>(Wk, Wv, Wr, Wo, gp_w, bp_w, wbf);

  for (int blk = 0; blk < 2; ++blk) {
    const u16* bWk = wbf + 0 * 32768 + blk * 16384;
    const u16* bWv = wbf + 1 * 32768 + blk * 16384;
    const u16* bWr = wbf + 2 * 32768 + blk * 16384;
    const u16* bWo = wbf + 3 * 32768 + blk * 16384;
    const u16* bGp = wbf + 4 * 32768 + blk * 16384;
    const u16* bBp = wbf + 5 * 32768 + blk * 16384;
    const float* tdi = td + blk * 128;

    if (blk == 0)
      prep_kernel<1><<<2048, 256, 0, stream>>>(x, gamma, beta, ln_g, ln_b, outp, xn);
    else
      prep_kernel<0><<<2048, 256, 0, stream>>>(outp, nullptr, nullptr, ln_g + 128,
                                               ln_b + 128, nullptr, xn);

    gemm_kvr_kernel<<<1024, 256, 0, stream>>>(xn, bWk, bWv, bWr, tdi,
                                              kbuf, vbuf, rbuf, Sbuf);
    scan2_kernel<<<256, 256, 0, stream>>>(Sbuf, tdi, ibuf);
    tail_kernel<<<1024, 512, 0, stream>>>(kbuf, vbuf, rbuf, ibuf, tdi,
                                          bWo, bGp, bBp, gp_b + blk * 128,
                                          bp_b + blk * 128, outp);
  }
}